// Round 15
// baseline (36.877 us; speedup 1.0000x reference)
//
#include <hip/hip_runtime.h>

#define L 512
#define LMASK 511
#define HID 32

constexpr int THREADS        = 256;
constexpr int ROWS_PER_BLOCK = 4;
constexpr int BLOCKS_PER_B   = L / ROWS_PER_BLOCK;   // 128
constexpr int NTAB           = 4096;                 // 1/64 cells, z' in [-32,32]
constexpr int NPAIR          = HID / 2;              // 16 exp pairs (B path)

// Magic addressing (A path): mantissa of (256*z' + 8194 + 2^23) = byte offset.
constexpr float MAGIC = 8388608.0f;                  // 2^23
constexpr float BIASB = 8194.0f;                     // 256*32 + 2 (half-cell center)

using v2f = __attribute__((ext_vector_type(2))) float;

// Heterogeneous-block hybrid: 3 of 8 blocks are TABLE blocks (LDS-gather pipe),
// 5 of 8 are EXP blocks (trans unit + packed VALU). Co-resident A+B blocks on
// one CU drive different pipes concurrently (m114 mechanism) — overlap that
// intra-wave interleaving (R7/R10/R11) could not achieve.
// Type selector uses blk>>3 so types mix WITHIN each XCD (blk&7 ~ XCD id).
__global__ __launch_bounds__(THREADS)
void site_kernel(const float* __restrict__ x,
                 const float* __restrict__ W1,
                 const float* __restrict__ b1,
                 const float* __restrict__ W2,
                 float* __restrict__ partial) {
    __shared__ __align__(16) float tab_s[NTAB];      // A: T(z')=1/(1+2^z')
    __shared__ __align__(16) float zw_s[8 * 16];     // A: 8 groups {wa4 wb4 wc4 w04}
    __shared__ __align__(16) float w2t_s[HID];       // A: -2*W2
    __shared__ __align__(16) float ew_s[NPAIR * 8];  // B: {wa01 wb01 wc01 w001}
    __shared__ __align__(8)  float ew2_s[NPAIR * 2]; // B: -2*W2 pairs

    const int t   = threadIdx.x;
    const int blk = blockIdx.x;
    const bool isA = ((blk >> 3) & 7) < 3;           // 3:5 table:exp
    const float Ke = 2.8853900817779268f;            // 2*log2(e)

    if (isA) {
        if (t < HID) {
            const float K256 = 256.0f * Ke;
            const int g = t >> 2, q = t & 3;
            zw_s[g * 16 +  0 + q] = K256 * W1[t * 3 + 0];
            zw_s[g * 16 +  4 + q] = K256 * W1[t * 3 + 1];
            zw_s[g * 16 +  8 + q] = K256 * W1[t * 3 + 2];
            zw_s[g * 16 + 12 + q] = fmaf(K256, b1[t], BIASB + MAGIC);
            w2t_s[t] = -2.0f * W2[t];                // tanh = 1 - 2*T
        }
        for (int i = t; i < NTAB; i += THREADS) {
            const float zp = fmaf((float)i, 0.015625f, -32.001953125f);
            tab_s[i] = __builtin_amdgcn_rcpf(1.0f + __builtin_amdgcn_exp2f(zp));
        }
    } else if (t < HID) {
        const int p = t >> 1, q = t & 1;
        ew_s[p * 8 + 0 + q] = Ke * W1[t * 3 + 0];
        ew_s[p * 8 + 2 + q] = Ke * W1[t * 3 + 1];
        ew_s[p * 8 + 4 + q] = Ke * W1[t * 3 + 2];
        ew_s[p * 8 + 6 + q] = Ke * b1[t];
        ew2_s[p * 2 + q]    = -2.0f * W2[t];
    }
    __syncthreads();

    const int b  = blk >> 7;                         // / BLOCKS_PER_B
    const int i0 = (blk & (BLOCKS_PER_B - 1)) * ROWS_PER_BLOCK;
    const float* __restrict__ xb = x + (size_t)b * (L * L);

    // Features for 8 sites: rows i0..i0+3, cols t and t+256.
    float F0[8], F1[8], F2[8];
#pragma unroll
    for (int g = 0; g < 2; ++g) {
        const int j  = t + g * THREADS;
        const int jm = (j + LMASK) & LMASK, jp = (j + 1) & LMASK;

        float cc[6];                                 // center col, rows i0-1..i0+4
#pragma unroll
        for (int r = 0; r < 6; ++r) {
            const int i = (i0 + r - 1 + L) & LMASK;
            cc[r] = xb[i * L + j];
        }
#pragma unroll
        for (int s = 0; s < 4; ++s) {
            const int i   = i0 + s;
            const float lf = xb[i * L + jm];
            const float rg = xb[i * L + jp];
            const float c  = cc[s + 1];
            const float lr = lf + rg;                // == sx
            const float x1 = lr + cc[s] + cc[s + 2];
            const int k = g * 4 + s;
            F0[k] = c * c;  F1[k] = x1 * c;  F2[k] = lr * c;
        }
    }

    float a;
    if (isA) {
        // ---- TABLE block: all 32 h via LDS gather (mask-only addressing) ----
        float acc[8] = {0.f, 0.f, 0.f, 0.f, 0.f, 0.f, 0.f, 0.f};
        const char* __restrict__ tb = (const char*)tab_s;
#pragma unroll 1
        for (int gq = 0; gq < 8; ++gq) {
            const float4 wa  = *(const float4*)&zw_s[gq * 16 + 0];
            const float4 wb  = *(const float4*)&zw_s[gq * 16 + 4];
            const float4 wc  = *(const float4*)&zw_s[gq * 16 + 8];
            const float4 w0  = *(const float4*)&zw_s[gq * 16 + 12];
            const float4 w2v = *(const float4*)&w2t_s[gq * 4];
#pragma unroll
            for (int q = 0; q < 4; ++q) {
                const float waq = ((const float*)&wa)[q];
                const float wbq = ((const float*)&wb)[q];
                const float wcq = ((const float*)&wc)[q];
                const float w0q = ((const float*)&w0)[q];
                const float w2q = ((const float*)&w2v)[q];
#pragma unroll
                for (int s = 0; s < 8; ++s) {
                    const float uu = fmaf(F0[s], waq, fmaf(F1[s], wbq, fmaf(F2[s], wcq, w0q)));
                    const int  off = __float_as_int(uu) & 0x3FFC;
                    const float y  = *reinterpret_cast<const float*>(tb + off);
                    acc[s] = fmaf(w2q, y, acc[s]);
                }
            }
        }
        a = ((acc[0] + acc[1]) + (acc[2] + acc[3]))
          + ((acc[4] + acc[5]) + (acc[6] + acc[7]));
    } else {
        // ---- EXP block: all 32 h via packed exp pairs (trans + pk-VALU) ----
        v2f F0v[4], F1v[4], F2v[4];
#pragma unroll
        for (int d = 0; d < 4; ++d) {
            F0v[d] = v2f{F0[2 * d], F0[2 * d + 1]};
            F1v[d] = v2f{F1[2 * d], F1[2 * d + 1]};
            F2v[d] = v2f{F2[2 * d], F2[2 * d + 1]};
        }
        v2f acc0 = {0.f, 0.f}, acc1 = {0.f, 0.f}, acc2 = {0.f, 0.f}, acc3 = {0.f, 0.f};
        const v2f one = {1.0f, 1.0f};
#pragma unroll 1
        for (int p = 0; p < NPAIR; ++p) {
            const float4 e0 = *(const float4*)&ew_s[p * 8 + 0];  // wa0 wa1 wb0 wb1
            const float4 e1 = *(const float4*)&ew_s[p * 8 + 4];  // wc0 wc1 w00 w01
            const float2 wp = *(const float2*)&ew2_s[p * 2];
            const v2f waa0 = {e0.x, e0.x}, waa1 = {e0.y, e0.y};
            const v2f wbb0 = {e0.z, e0.z}, wbb1 = {e0.w, e0.w};
            const v2f wcc0 = {e1.x, e1.x}, wcc1 = {e1.y, e1.y};
            const v2f w000 = {e1.z, e1.z}, w001 = {e1.w, e1.w};
            const v2f w2xx = {wp.x, wp.x}, w2yy = {wp.y, wp.y};
#pragma unroll
            for (int d = 0; d < 4; ++d) {
                const v2f z0 = __builtin_elementwise_fma(F0v[d], waa0,
                               __builtin_elementwise_fma(F1v[d], wbb0,
                               __builtin_elementwise_fma(F2v[d], wcc0, w000)));
                const v2f z1 = __builtin_elementwise_fma(F0v[d], waa1,
                               __builtin_elementwise_fma(F1v[d], wbb1,
                               __builtin_elementwise_fma(F2v[d], wcc1, w001)));
                const v2f ex0 = {__builtin_amdgcn_exp2f(z0.x), __builtin_amdgcn_exp2f(z0.y)};
                const v2f ex1 = {__builtin_amdgcn_exp2f(z1.x), __builtin_amdgcn_exp2f(z1.y)};
                const v2f d0 = ex0 + one;
                const v2f d1 = ex1 + one;
                const v2f nm = __builtin_elementwise_fma(w2yy, d0, w2xx * d1);
                const v2f D  = d0 * d1;
                const v2f rr = {__builtin_amdgcn_rcpf(D.x), __builtin_amdgcn_rcpf(D.y)};
                const v2f contrib = nm * rr;
                if      (d == 0) acc0 += contrib;
                else if (d == 1) acc1 += contrib;
                else if (d == 2) acc2 += contrib;
                else             acc3 += contrib;
            }
        }
        a = ((acc0.x + acc0.y) + (acc1.x + acc1.y))
          + ((acc2.x + acc2.y) + (acc3.x + acc3.y));
    }

#pragma unroll
    for (int off = 32; off > 0; off >>= 1)
        a += __shfl_down(a, off, 64);

    __shared__ float wsum[THREADS / 64];
    const int wid = t >> 6, lane = t & 63;
    if (lane == 0) wsum[wid] = a;
    __syncthreads();
    if (t == 0)
        partial[blk] = (wsum[0] + wsum[1]) + (wsum[2] + wsum[3]);
}

// Deterministic fixed-order reduction + folded tanh constant.
__global__ __launch_bounds__(128)
void reduce_kernel(const float* __restrict__ partial,
                   const float* __restrict__ W2,
                   const float* __restrict__ b2,
                   float* __restrict__ out) {
    const int b = blockIdx.x, t = threadIdx.x;
    const float NS = (float)(L * L);                 // 262144 sites per config

    float v = partial[b * BLOCKS_PER_B + t];
    if (t < HID) v += NS * W2[t];                    // + L^2 * sum_h W2[h]
    if (t == 0)  v += NS * b2[0];                    // + L^2 * b2

#pragma unroll
    for (int off = 32; off > 0; off >>= 1)
        v += __shfl_down(v, off, 64);

    __shared__ float ws2[2];
    if ((t & 63) == 0) ws2[t >> 6] = v;
    __syncthreads();
    if (t == 0) out[b] = ws2[0] + ws2[1];
}

extern "C" void kernel_launch(void* const* d_in, const int* in_sizes, int n_in,
                              void* d_out, int out_size, void* d_ws, size_t ws_size,
                              hipStream_t stream) {
    const float* x  = (const float*)d_in[0];
    const float* W1 = (const float*)d_in[1];
    const float* b1 = (const float*)d_in[2];
    const float* W2 = (const float*)d_in[3];
    const float* b2 = (const float*)d_in[4];
    float* out      = (float*)d_out;
    float* partial  = (float*)d_ws;                  // 2048 floats

    const int B = in_sizes[0] / (L * L);             // 16

    site_kernel<<<B * BLOCKS_PER_B, THREADS, 0, stream>>>(x, W1, b1, W2, partial);
    reduce_kernel<<<B, 128, 0, stream>>>(partial, W2, b2, out);
}

// Round 16
// 34.926 us; speedup vs baseline: 1.0558x; 1.0558x over previous
//
#include <hip/hip_runtime.h>

#define L 512
#define LMASK 511
#define HID 32

constexpr int THREADS        = 256;
constexpr int ROWS_PER_BLOCK = 4;
constexpr int BLOCKS_PER_B   = L / ROWS_PER_BLOCK;   // 128
constexpr int NPAIR          = HID / 2;              // 16 exp pairs

using v2f = __attribute__((ext_vector_type(2))) float;

// CDNA dual-FP32 packed ops (64-bit VGPR pairs) — forced via inline asm so the
// backend cannot scalarize. Numerically identical to per-lane fmaf/add/mul.
static __device__ __forceinline__ v2f pk_fma(v2f a, v2f b, v2f c) {
    v2f d;
    asm("v_pk_fma_f32 %0, %1, %2, %3" : "=v"(d) : "v"(a), "v"(b), "v"(c));
    return d;
}
static __device__ __forceinline__ v2f pk_add(v2f a, v2f b) {
    v2f d;
    asm("v_pk_add_f32 %0, %1, %2" : "=v"(d) : "v"(a), "v"(b));
    return d;
}
static __device__ __forceinline__ v2f pk_mul(v2f a, v2f b) {
    v2f d;
    asm("v_pk_mul_f32 %0, %1, %2" : "=v"(d) : "v"(a), "v"(b));
    return d;
}

// Pure-exp MLP, site-packed float2 via real v_pk_*_f32, pair-shared rcp.
// tanh(y) = 1 - 2/(1+e^{2y}); w2a/d0 + w2b/d1 = (w2a*d1+w2b*d0)/(d0*d1).
// Unclamped is safe: d in [1, 1+2^~60] -> product < 2^121 finite (R13/R14).
__global__ __launch_bounds__(THREADS)
void site_kernel(const float* __restrict__ x,
                 const float* __restrict__ W1,
                 const float* __restrict__ b1,
                 const float* __restrict__ W2,
                 float* __restrict__ partial) {
    __shared__ __align__(16) float ew_s[NPAIR * 8];  // {wa01 wb01 wc01 w001} per pair
    __shared__ __align__(8)  float ew2_s[NPAIR * 2]; // -2*W2 per pair

    const int t = threadIdx.x;
    const float Ke = 2.8853900817779268f;            // 2*log2(e)

    if (t < HID) {
        const int p = t >> 1, q = t & 1;
        ew_s[p * 8 + 0 + q] = Ke * W1[t * 3 + 0];
        ew_s[p * 8 + 2 + q] = Ke * W1[t * 3 + 1];
        ew_s[p * 8 + 4 + q] = Ke * W1[t * 3 + 2];
        ew_s[p * 8 + 6 + q] = Ke * b1[t];
        ew2_s[p * 2 + q]    = -2.0f * W2[t];         // tanh = 1 - 2*T
    }
    __syncthreads();

    const int blk = blockIdx.x;
    const int b   = blk >> 7;                        // / BLOCKS_PER_B
    const int i0  = (blk & (BLOCKS_PER_B - 1)) * ROWS_PER_BLOCK;
    const float* __restrict__ xb = x + (size_t)b * (L * L);

    // Features for 8 sites: rows i0..i0+3, cols t and t+256.
    float F0[8], F1[8], F2[8];
#pragma unroll
    for (int g = 0; g < 2; ++g) {
        const int j  = t + g * THREADS;
        const int jm = (j + LMASK) & LMASK, jp = (j + 1) & LMASK;

        float cc[6];                                 // center col, rows i0-1..i0+4
#pragma unroll
        for (int r = 0; r < 6; ++r) {
            const int i = (i0 + r - 1 + L) & LMASK;
            cc[r] = xb[i * L + j];
        }
#pragma unroll
        for (int s = 0; s < 4; ++s) {
            const int i   = i0 + s;
            const float lf = xb[i * L + jm];
            const float rg = xb[i * L + jp];
            const float c  = cc[s + 1];
            const float lr = lf + rg;                // == sx
            const float x1 = lr + cc[s] + cc[s + 2];
            const int k = g * 4 + s;
            F0[k] = c * c;  F1[k] = x1 * c;  F2[k] = lr * c;
        }
    }

    // Pack sites into duos: duo d = sites (2d, 2d+1).
    v2f F0v[4], F1v[4], F2v[4];
#pragma unroll
    for (int d = 0; d < 4; ++d) {
        F0v[d] = v2f{F0[2 * d], F0[2 * d + 1]};
        F1v[d] = v2f{F1[2 * d], F1[2 * d + 1]};
        F2v[d] = v2f{F2[2 * d], F2[2 * d + 1]};
    }

    v2f acc0 = {0.f, 0.f}, acc1 = {0.f, 0.f}, acc2 = {0.f, 0.f}, acc3 = {0.f, 0.f};
    const v2f one = {1.0f, 1.0f};

#pragma unroll 1
    for (int p = 0; p < NPAIR; ++p) {
        const float4 e0 = *(const float4*)&ew_s[p * 8 + 0];  // wa0 wa1 wb0 wb1
        const float4 e1 = *(const float4*)&ew_s[p * 8 + 4];  // wc0 wc1 w00 w01
        const float2 wp = *(const float2*)&ew2_s[p * 2];
        const v2f waa0 = {e0.x, e0.x}, waa1 = {e0.y, e0.y};
        const v2f wbb0 = {e0.z, e0.z}, wbb1 = {e0.w, e0.w};
        const v2f wcc0 = {e1.x, e1.x}, wcc1 = {e1.y, e1.y};
        const v2f w000 = {e1.z, e1.z}, w001 = {e1.w, e1.w};
        const v2f w2xx = {wp.x, wp.x}, w2yy = {wp.y, wp.y};

#pragma unroll
        for (int d = 0; d < 4; ++d) {
            const v2f z0 = pk_fma(F0v[d], waa0, pk_fma(F1v[d], wbb0, pk_fma(F2v[d], wcc0, w000)));
            const v2f z1 = pk_fma(F0v[d], waa1, pk_fma(F1v[d], wbb1, pk_fma(F2v[d], wcc1, w001)));
            v2f ex0, ex1;
            ex0.x = __builtin_amdgcn_exp2f(z0.x);
            ex0.y = __builtin_amdgcn_exp2f(z0.y);
            ex1.x = __builtin_amdgcn_exp2f(z1.x);
            ex1.y = __builtin_amdgcn_exp2f(z1.y);
            const v2f d0 = pk_add(ex0, one);
            const v2f d1 = pk_add(ex1, one);
            const v2f nm = pk_fma(w2yy, d0, pk_mul(w2xx, d1));  // w2a/d0 + w2b/d1
            const v2f D  = pk_mul(d0, d1);
            v2f rr;
            rr.x = __builtin_amdgcn_rcpf(D.x);
            rr.y = __builtin_amdgcn_rcpf(D.y);
            if      (d == 0) acc0 = pk_fma(nm, rr, acc0);
            else if (d == 1) acc1 = pk_fma(nm, rr, acc1);
            else if (d == 2) acc2 = pk_fma(nm, rr, acc2);
            else             acc3 = pk_fma(nm, rr, acc3);
        }
    }

    float a = ((acc0.x + acc0.y) + (acc1.x + acc1.y))
            + ((acc2.x + acc2.y) + (acc3.x + acc3.y));
#pragma unroll
    for (int off = 32; off > 0; off >>= 1)
        a += __shfl_down(a, off, 64);

    __shared__ float wsum[THREADS / 64];
    const int wid = t >> 6, lane = t & 63;
    if (lane == 0) wsum[wid] = a;
    __syncthreads();
    if (t == 0)
        partial[blk] = (wsum[0] + wsum[1]) + (wsum[2] + wsum[3]);
}

// Deterministic fixed-order reduction + folded tanh constant.
__global__ __launch_bounds__(128)
void reduce_kernel(const float* __restrict__ partial,
                   const float* __restrict__ W2,
                   const float* __restrict__ b2,
                   float* __restrict__ out) {
    const int b = blockIdx.x, t = threadIdx.x;
    const float NS = (float)(L * L);                 // 262144 sites per config

    float v = partial[b * BLOCKS_PER_B + t];
    if (t < HID) v += NS * W2[t];                    // + L^2 * sum_h W2[h]
    if (t == 0)  v += NS * b2[0];                    // + L^2 * b2

#pragma unroll
    for (int off = 32; off > 0; off >>= 1)
        v += __shfl_down(v, off, 64);

    __shared__ float ws2[2];
    if ((t & 63) == 0) ws2[t >> 6] = v;
    __syncthreads();
    if (t == 0) out[b] = ws2[0] + ws2[1];
}

extern "C" void kernel_launch(void* const* d_in, const int* in_sizes, int n_in,
                              void* d_out, int out_size, void* d_ws, size_t ws_size,
                              hipStream_t stream) {
    const float* x  = (const float*)d_in[0];
    const float* W1 = (const float*)d_in[1];
    const float* b1 = (const float*)d_in[2];
    const float* W2 = (const float*)d_in[3];
    const float* b2 = (const float*)d_in[4];
    float* out      = (float*)d_out;
    float* partial  = (float*)d_ws;                  // 2048 floats

    const int B = in_sizes[0] / (L * L);             // 16

    site_kernel<<<B * BLOCKS_PER_B, THREADS, 0, stream>>>(x, W1, b1, W2, partial);
    reduce_kernel<<<B, 128, 0, stream>>>(partial, W2, b2, out);
}

// Round 17
// 33.773 us; speedup vs baseline: 1.0919x; 1.0341x over previous
//
#include <hip/hip_runtime.h>

#define L 512
#define LMASK 511
#define HID 32

constexpr int THREADS        = 256;
constexpr int ROWS_PER_BLOCK = 2;
constexpr int BLOCKS_PER_B   = L / ROWS_PER_BLOCK;   // 256
constexpr int NTAB           = 4096;                 // 1/64 cells, z' in [-32,32]
constexpr int GT             = 5;                    // table groups (20 h)
constexpr int NPAIR_E        = 6;                    // exp pairs (12 h)

constexpr float MAGIC = 8388608.0f;                  // 2^23
constexpr float BIASB = 8194.0f;                     // 256*32 + 2 (half-cell center)

// R17: hybrid with issue-then-consume pipelining. Each table group's 16
// ds_reads are issued into temps BEFORE an exp-pair's trans burst; the LDS
// pipe resolves the gathers underneath the ~384-cyc trans work, and the
// consume fmas run afterwards. Breaks the load->use serialization that made
// R7/R10/R11/R13 behave as serial phase sums.
__global__ __launch_bounds__(THREADS)
void site_kernel(const float* __restrict__ x,
                 const float* __restrict__ W1,
                 const float* __restrict__ b1,
                 const float* __restrict__ W2,
                 float* __restrict__ partial) {
    __shared__ __align__(16) float tab_s[NTAB];      // T(z')=1/(1+2^z'), nearest
    __shared__ __align__(16) float zw_s[GT * 16];    // table groups {wa4 wb4 wc4 w04}
    __shared__ __align__(16) float w2t_s[GT * 4];    // table-path w2
    __shared__ __align__(16) float ew_s[NPAIR_E * 8];// exp pairs {wa01 wb01 wc01 w001}
    __shared__ __align__(8)  float ew2_s[NPAIR_E * 2];

    const int t = threadIdx.x;
    const float Ke = 2.8853900817779268f;            // 2*log2(e)

    if (t < HID) {
        if (t < 4 * GT) {                            // table-path h
            const float K256 = 256.0f * Ke;
            const int g = t >> 2, q = t & 3;
            zw_s[g * 16 +  0 + q] = K256 * W1[t * 3 + 0];
            zw_s[g * 16 +  4 + q] = K256 * W1[t * 3 + 1];
            zw_s[g * 16 +  8 + q] = K256 * W1[t * 3 + 2];
            zw_s[g * 16 + 12 + q] = fmaf(K256, b1[t], BIASB + MAGIC);
            w2t_s[t] = -2.0f * W2[t];                // tanh = 1 - 2*T
        } else {                                     // exp-path h
            const int e = t - 4 * GT, p = e >> 1, q = e & 1;
            ew_s[p * 8 + 0 + q] = Ke * W1[t * 3 + 0];
            ew_s[p * 8 + 2 + q] = Ke * W1[t * 3 + 1];
            ew_s[p * 8 + 4 + q] = Ke * W1[t * 3 + 2];
            ew_s[p * 8 + 6 + q] = Ke * b1[t];
            ew2_s[p * 2 + q]    = -2.0f * W2[t];
        }
    }
    for (int i = t; i < NTAB; i += THREADS) {
        const float zp = fmaf((float)i, 0.015625f, -32.001953125f);
        tab_s[i] = __builtin_amdgcn_rcpf(1.0f + __builtin_amdgcn_exp2f(zp));
    }
    __syncthreads();

    const int blk = blockIdx.x;
    const int b   = blk >> 8;                        // / BLOCKS_PER_B
    const int i0  = (blk & (BLOCKS_PER_B - 1)) * ROWS_PER_BLOCK;
    const float* __restrict__ xb = x + (size_t)b * (L * L);

    // Features for 4 sites: rows i0,i0+1, cols t and t+256.
    float F0[4], F1[4], F2[4];
#pragma unroll
    for (int g = 0; g < 2; ++g) {
        const int j  = t + g * THREADS;
        const int jm = (j + LMASK) & LMASK, jp = (j + 1) & LMASK;

        float cc[4];                                 // center col, rows i0-1..i0+2
#pragma unroll
        for (int r = 0; r < 4; ++r) {
            const int i = (i0 + r - 1 + L) & LMASK;
            cc[r] = xb[i * L + j];
        }
#pragma unroll
        for (int s = 0; s < 2; ++s) {
            const int i   = i0 + s;
            const float lf = xb[i * L + jm];
            const float rg = xb[i * L + jp];
            const float c  = cc[s + 1];
            const float lr = lf + rg;                // == sx
            const float x1 = lr + cc[s] + cc[s + 2];
            const int k = g * 2 + s;
            F0[k] = c * c;  F1[k] = x1 * c;  F2[k] = lr * c;
        }
    }

    float acc[4] = {0.f, 0.f, 0.f, 0.f};
    const char* __restrict__ tb = (const char*)tab_s;

    int   offs[16];                                  // static-indexed (reg-resident)
    float tt[16];

    // Phase 1: compute this tgroup's 16 table addresses.
    auto taddr = [&](const int gq) {
        const float4 wa = *(const float4*)&zw_s[gq * 16 + 0];
        const float4 wb = *(const float4*)&zw_s[gq * 16 + 4];
        const float4 wc = *(const float4*)&zw_s[gq * 16 + 8];
        const float4 w0 = *(const float4*)&zw_s[gq * 16 + 12];
#pragma unroll
        for (int q = 0; q < 4; ++q) {
            const float waq = ((const float*)&wa)[q];
            const float wbq = ((const float*)&wb)[q];
            const float wcq = ((const float*)&wc)[q];
            const float w0q = ((const float*)&w0)[q];
#pragma unroll
            for (int s = 0; s < 4; ++s) {
                const float uu = fmaf(F0[s], waq, fmaf(F1[s], wbq, fmaf(F2[s], wcq, w0q)));
                offs[q * 4 + s] = __float_as_int(uu) & 0x3FFC;
            }
        }
    };
    // Phase 2: issue all 16 gathers (no consumption -> no lgkmcnt stall here).
    auto tload = [&]() {
#pragma unroll
        for (int i = 0; i < 16; ++i)
            tt[i] = *reinterpret_cast<const float*>(tb + offs[i]);
    };
    // Phase 4: consume gathered values.
    auto tcons = [&](const int gq) {
        const float4 w2v = *(const float4*)&w2t_s[gq * 4];
#pragma unroll
        for (int q = 0; q < 4; ++q) {
            const float w2q = ((const float*)&w2v)[q];
#pragma unroll
            for (int s = 0; s < 4; ++s)
                acc[s] = fmaf(w2q, tt[q * 4 + s], acc[s]);
        }
    };
    // Phase 3 (between issue and consume): one exp pair's trans burst.
    auto epair = [&](const int p) {
        const float4 e0 = *(const float4*)&ew_s[p * 8 + 0];  // wa0 wa1 wb0 wb1
        const float4 e1 = *(const float4*)&ew_s[p * 8 + 4];  // wc0 wc1 w00 w01
        const float2 wp = *(const float2*)&ew2_s[p * 2];
        const float wa0 = e0.x, wa1 = e0.y, wb0 = e0.z, wb1 = e0.w;
        const float wc0 = e1.x, wc1 = e1.y, w00 = e1.z, w01 = e1.w;
#pragma unroll
        for (int s = 0; s < 4; ++s) {
            const float z0 = fmaf(F0[s], wa0, fmaf(F1[s], wb0, fmaf(F2[s], wc0, w00)));
            const float z1 = fmaf(F0[s], wa1, fmaf(F1[s], wb1, fmaf(F2[s], wc1, w01)));
            const float d0 = 1.0f + __builtin_amdgcn_exp2f(z0);
            const float d1 = 1.0f + __builtin_amdgcn_exp2f(z1);
            const float nm = fmaf(wp.x, d1, wp.y * d0);   // w2a/d0 + w2b/d1
            const float rr = __builtin_amdgcn_rcpf(d0 * d1);
            acc[s] = fmaf(nm, rr, acc[s]);
        }
    };

    // Pipelined schedule: gathers of group g resolve during epair(g)'s trans.
    taddr(0); tload(); epair(0); tcons(0);
    taddr(1); tload(); epair(1); tcons(1);
    taddr(2); tload(); epair(2); tcons(2);
    taddr(3); tload(); epair(3); tcons(3);
    taddr(4); tload(); epair(4); tcons(4);
    epair(5);

    float a = (acc[0] + acc[1]) + (acc[2] + acc[3]);
#pragma unroll
    for (int off = 32; off > 0; off >>= 1)
        a += __shfl_down(a, off, 64);

    __shared__ float wsum[THREADS / 64];
    const int wid = t >> 6, lane = t & 63;
    if (lane == 0) wsum[wid] = a;
    __syncthreads();
    if (t == 0)
        partial[blk] = (wsum[0] + wsum[1]) + (wsum[2] + wsum[3]);
}

// Deterministic fixed-order reduction + folded tanh constant.
__global__ __launch_bounds__(256)
void reduce_kernel(const float* __restrict__ partial,
                   const float* __restrict__ W2,
                   const float* __restrict__ b2,
                   float* __restrict__ out) {
    const int b = blockIdx.x, t = threadIdx.x;
    const float NS = (float)(L * L);                 // 262144 sites per config

    float v = partial[b * BLOCKS_PER_B + t];
    if (t < HID) v += NS * W2[t];                    // + L^2 * sum_h W2[h]
    if (t == 0)  v += NS * b2[0];                    // + L^2 * b2

#pragma unroll
    for (int off = 32; off > 0; off >>= 1)
        v += __shfl_down(v, off, 64);

    __shared__ float ws4[4];
    if ((t & 63) == 0) ws4[t >> 6] = v;
    __syncthreads();
    if (t == 0) out[b] = (ws4[0] + ws4[1]) + (ws4[2] + ws4[3]);
}

extern "C" void kernel_launch(void* const* d_in, const int* in_sizes, int n_in,
                              void* d_out, int out_size, void* d_ws, size_t ws_size,
                              hipStream_t stream) {
    const float* x  = (const float*)d_in[0];
    const float* W1 = (const float*)d_in[1];
    const float* b1 = (const float*)d_in[2];
    const float* W2 = (const float*)d_in[3];
    const float* b2 = (const float*)d_in[4];
    float* out      = (float*)d_out;
    float* partial  = (float*)d_ws;                  // 4096 floats

    const int B = in_sizes[0] / (L * L);             // 16

    site_kernel<<<B * BLOCKS_PER_B, THREADS, 0, stream>>>(x, W1, b1, W2, partial);
    reduce_kernel<<<B, 256, 0, stream>>>(partial, W2, b2, out);
}